// Round 5
// baseline (292.504 us; speedup 1.0000x reference)
//
#include <hip/hip_runtime.h>
#include <hip/hip_bf16.h>
#include <stdint.h>
#include <stddef.h>

// GlobalLSTMCell — f32 in/out, bf16 MFMA compute.
//   ifo = sigmoid(x@W_ifo_x + b_ifo_x + h@W_ifo_h + b_ifo_h); i,f,o = split
//   a   = tanh(x@W_b_x + b_b_x + h@W_b_h + b_b_h)
//   c   = i*a + f*c_prev ; h = o*tanh(c) ; out = [h ; c] f32.
// R4 lessons: SQ_LDS_BANK_CONFLICT = 4/ds_read_b128 is the b128 structural
// floor (8 lanes/quad-bank-group), NOT waste — swizzle reverted. Pack fusion
// saved ~0 -> gap is pack work or fixed overhead. This round: xh_pack is GONE —
// GEMM stages A directly from f32 x/h with in-register cvt; XOR chunk placement
// (p = c ^ (r&3)) keeps A LDS stores AND fragment reads at the b128 floor.
// B operand still global_load_lds(16B) from pre-packed Wt (wt_pack).

#define BATCH 4096
#define FEAT  1024
#define HID   1024
#define NCAT  4096
#define KCAT  2048

typedef __attribute__((ext_vector_type(8))) __bf16 bf16x8;
typedef __attribute__((ext_vector_type(4))) float  floatx4;

__device__ __forceinline__ unsigned short f2bf(float f) {
    __hip_bfloat16 b = __float2bfloat16(f);
    return *reinterpret_cast<unsigned short*>(&b);
}
__device__ __forceinline__ void gl2lds16(const unsigned short* g, unsigned short* l) {
    __builtin_amdgcn_global_load_lds(
        (const __attribute__((address_space(1))) void*)g,
        (__attribute__((address_space(3))) void*)l, 16, 0, 0);
}

// ---------------- weight pack/transpose ----------------
// Virtual W_cat[k][q]: k<1024 x-weights else h-weights; q<3072 -> W_ifo (g=q>>10,
// j=q&1023) else W_b (g=3, j=q-3072). Dest Wt[np][k], np=(j>>4)*64+g*16+(j&15).
#define TP_PAD 72   // u16 row stride; 144 B -> uint4-aligned rows
__global__ __launch_bounds__(256)
void wt_pack(const float* __restrict__ Wix, const float* __restrict__ Wih,
             const float* __restrict__ Wbx, const float* __restrict__ Wbh,
             unsigned short* __restrict__ Wt) {
    __shared__ unsigned short tile[64 * TP_PAD];
    const int t  = threadIdx.x;
    const int k0 = (blockIdx.x & 31) * 64;
    const int q0 = (blockIdx.x >> 5) * 64;
    const float* src; int stride, cb;
    if (q0 < 3072) { src = (k0 < FEAT) ? Wix : Wih; stride = 3072; cb = q0; }
    else           { src = (k0 < FEAT) ? Wbx : Wbh; stride = 1024; cb = q0 - 3072; }
    const int krow = (k0 < FEAT) ? k0 : (k0 - FEAT);
    {   // load 64x64 (k x q) coalesced on q, cvt bf16, vector LDS stores
        int kl = t >> 2;
        int c0 = (t & 3) * 16;
        const float* s = src + (size_t)(krow + kl) * stride + cb + c0;
        union { unsigned short s16[16]; uint4 v[2]; } tmp;
#pragma unroll
        for (int u = 0; u < 16; u += 4) {
            float4 v = *(const float4*)(s + u);
            tmp.s16[u + 0] = f2bf(v.x); tmp.s16[u + 1] = f2bf(v.y);
            tmp.s16[u + 2] = f2bf(v.z); tmp.s16[u + 3] = f2bf(v.w);
        }
        *(uint4*)&tile[kl * TP_PAD + c0]     = tmp.v[0];
        *(uint4*)&tile[kl * TP_PAD + c0 + 8] = tmp.v[1];
    }
    __syncthreads();
    {   // transpose out: thread = (q-col nl, k-chunk seg)
        int nl = t >> 2, seg = t & 3;
        int q = q0 + nl;
        int g, j;
        if (q < 3072) { g = q >> 10; j = q & 1023; }
        else          { g = 3;       j = q - 3072; }
        int np = ((j >> 4) << 6) + (g << 4) + (j & 15);
        union { unsigned short s16[16]; uint4 v[2]; } pk;
#pragma unroll
        for (int u = 0; u < 16; ++u)
            pk.s16[u] = tile[(seg * 16 + u) * TP_PAD + nl];
        uint4* dst = (uint4*)(Wt + (size_t)np * KCAT + k0 + seg * 16);
        dst[0] = pk.v[0];
        dst[1] = pk.v[1];
    }
}

// ---------------- fused GEMM + LSTM epilogue ----------------
#define BM 128
#define BN 128
#define BK 32

__device__ __forceinline__ uint4 cvt8(float4 a, float4 b) {
    union { unsigned short s16[8]; uint4 v; } pk;
    pk.s16[0] = f2bf(a.x); pk.s16[1] = f2bf(a.y);
    pk.s16[2] = f2bf(a.z); pk.s16[3] = f2bf(a.w);
    pk.s16[4] = f2bf(b.x); pk.s16[5] = f2bf(b.y);
    pk.s16[6] = f2bf(b.z); pk.s16[7] = f2bf(b.w);
    return pk.v;
}

__global__ __launch_bounds__(256)
void lstm_fused(const float* __restrict__ x, const float* __restrict__ hp,
                const unsigned short* __restrict__ Wt,
                const float* __restrict__ c_prev,
                const float* __restrict__ bix, const float* __restrict__ bih,
                const float* __restrict__ bbx, const float* __restrict__ bbh,
                float* __restrict__ out_h, float* __restrict__ out_c) {
    __shared__ unsigned short As[BM * BK];   // 8 KB
    __shared__ unsigned short Bs[BN * BK];   // 8 KB
    const int t    = threadIdx.x;
    const int lane = t & 63;
    const int wave = t >> 6;
    const int wm   = (wave >> 1) * 64;
    const int wn   = (wave & 1) * 64;
    const int m0   = blockIdx.y * BM;
    const int n0   = blockIdx.x * BN;

    floatx4 acc[4][4];
#pragma unroll
    for (int i = 0; i < 4; ++i)
#pragma unroll
        for (int g = 0; g < 4; ++g) acc[i][g] = (floatx4){0.f, 0.f, 0.f, 0.f};

    // Staging mapping: r = t>>2 (row), p = t&3 (physical 8-u16 chunk slot).
    // A physical slot p holds logical chunk p ^ (r&3)  -> stores at b128 floor.
    const int r    = t >> 2;
    const int p    = t & 3;
    const int lsub = ((p ^ (r & 3)) * 8);   // logical k-offset fetched (A, floats)
    const int bcol = p * 8;                 // B logical chunk (dest fixed by gl2lds)

    // Fragment constants: logical chunk q of row rho lives at q ^ (rho&3).
    const int lm = lane & 15;
    const int qh = lane >> 4;
    const int pa = ((qh ^ (lm & 3)) * 8);
    const int pb = qh * 8;

    for (int kk = 0; kk < KCAT; kk += BK) {
        const float* Arow = (kk < FEAT)
            ? (x  + (size_t)(m0 + r) * FEAT + kk + lsub)
            : (hp + (size_t)(m0 + r) * FEAT + (kk - FEAT) + lsub);
        float4 a0 = *(const float4*)Arow;
        float4 a1 = *(const float4*)(Arow + 4);
        float4 a2 = *(const float4*)(Arow + (size_t)64 * FEAT);
        float4 a3 = *(const float4*)(Arow + (size_t)64 * FEAT + 4);
        uint4 c0 = cvt8(a0, a1);
        uint4 c1 = cvt8(a2, a3);
        __syncthreads();   // previous tile fully consumed
        gl2lds16(Wt + (size_t)(n0 + r)      * KCAT + kk + bcol, &Bs[t * 8]);
        gl2lds16(Wt + (size_t)(n0 + r + 64) * KCAT + kk + bcol, &Bs[t * 8 + 2048]);
        *(uint4*)&As[r * BK + p * 8]          = c0;
        *(uint4*)&As[(r + 64) * BK + p * 8]   = c1;
        __syncthreads();   // drains lgkm (ds_write) + vmcnt (gl2lds)

        bf16x8 a[4], b[4];
#pragma unroll
        for (int i = 0; i < 4; ++i)
            a[i] = *(const bf16x8*)&As[(wm + i * 16 + lm) * BK + pa];
#pragma unroll
        for (int g = 0; g < 4; ++g)
            b[g] = *(const bf16x8*)&Bs[(wn + g * 16 + lm) * BK + pb];
#pragma unroll
        for (int i = 0; i < 4; ++i)
#pragma unroll
            for (int g = 0; g < 4; ++g)
                acc[i][g] = __builtin_amdgcn_mfma_f32_16x16x32_bf16(a[i], b[g], acc[i][g], 0, 0, 0);
    }

    // Epilogue: acc[i][g][r] = preact of gate g (i,f,o,a) at
    // m = m0+wm+i*16+(lane>>4)*4+rr, j = ((n0+wn)>>6)*16 + lm.
    const int j  = (((n0 + wn) >> 6) << 4) + lm;
    const float bi = bix[j]           + bih[j];
    const float bf = bix[HID + j]     + bih[HID + j];
    const float bo = bix[2 * HID + j] + bih[2 * HID + j];
    const float ba = bbx[j]           + bbh[j];
#pragma unroll
    for (int i = 0; i < 4; ++i) {
#pragma unroll
        for (int rr = 0; rr < 4; ++rr) {
            int m = m0 + wm + i * 16 + (qh * 4) + rr;
            float pi = acc[i][0][rr] + bi;
            float pf = acc[i][1][rr] + bf;
            float po = acc[i][2][rr] + bo;
            float pa2 = acc[i][3][rr] + ba;
            float ig = 1.f / (1.f + __expf(-pi));
            float fg = 1.f / (1.f + __expf(-pf));
            float og = 1.f / (1.f + __expf(-po));
            float av = 2.f / (1.f + __expf(-2.f * pa2)) - 1.f;
            float cp = c_prev[(size_t)m * HID + j];
            float cv = ig * av + fg * cp;
            float hv = og * (2.f / (1.f + __expf(-2.f * cv)) - 1.f);
            out_h[(size_t)m * HID + j] = hv;
            out_c[(size_t)m * HID + j] = cv;
        }
    }
}

// ---------------- naive fallback (ws too small) ----------------
__global__ void naive_lstm(const float* __restrict__ x, const float* __restrict__ h,
                           const float* __restrict__ cvp,
                           const float* __restrict__ Wix, const float* __restrict__ bix,
                           const float* __restrict__ Wih, const float* __restrict__ bih,
                           const float* __restrict__ Wbx, const float* __restrict__ bbx,
                           const float* __restrict__ Wbh, const float* __restrict__ bbh,
                           float* __restrict__ out_h, float* __restrict__ out_c) {
    const int j = blockIdx.x * 256 + threadIdx.x;
    const int m = blockIdx.y;
    float ai = 0.f, af = 0.f, ao = 0.f, aa = 0.f;
    for (int k = 0; k < FEAT; ++k) {
        float xk = x[(size_t)m * FEAT + k];
        ai += xk * Wix[(size_t)k * 3072 + j];
        af += xk * Wix[(size_t)k * 3072 + HID + j];
        ao += xk * Wix[(size_t)k * 3072 + 2 * HID + j];
        aa += xk * Wbx[(size_t)k * HID + j];
    }
    for (int k = 0; k < HID; ++k) {
        float hk = h[(size_t)m * HID + k];
        ai += hk * Wih[(size_t)k * 3072 + j];
        af += hk * Wih[(size_t)k * 3072 + HID + j];
        ao += hk * Wih[(size_t)k * 3072 + 2 * HID + j];
        aa += hk * Wbh[(size_t)k * HID + j];
    }
    ai += bix[j] + bih[j];
    af += bix[HID + j] + bih[HID + j];
    ao += bix[2 * HID + j] + bih[2 * HID + j];
    aa += bbx[j] + bbh[j];
    float ig = 1.f / (1.f + __expf(-ai));
    float fg = 1.f / (1.f + __expf(-af));
    float og = 1.f / (1.f + __expf(-ao));
    float av = 2.f / (1.f + __expf(-2.f * aa)) - 1.f;
    float cp = cvp[(size_t)m * HID + j];
    float cc = ig * av + fg * cp;
    float hh = og * (2.f / (1.f + __expf(-2.f * cc)) - 1.f);
    out_h[(size_t)m * HID + j] = hh;
    out_c[(size_t)m * HID + j] = cc;
}

extern "C" void kernel_launch(void* const* d_in, const int* in_sizes, int n_in,
                              void* d_out, int out_size, void* d_ws, size_t ws_size,
                              hipStream_t stream) {
    const float* x   = (const float*)d_in[0];
    const float* h   = (const float*)d_in[1];
    const float* c   = (const float*)d_in[2];
    const float* Wix = (const float*)d_in[3];
    const float* bix = (const float*)d_in[4];
    const float* Wih = (const float*)d_in[5];
    const float* bih = (const float*)d_in[6];
    const float* Wbx = (const float*)d_in[7];
    const float* bbx = (const float*)d_in[8];
    const float* Wbh = (const float*)d_in[9];
    const float* bbh = (const float*)d_in[10];

    float* out_h = (float*)d_out;
    float* out_c = out_h + (size_t)BATCH * HID;

    const size_t WT_BYTES = (size_t)NCAT * KCAT * 2;    // 16 MiB
    if (ws_size >= WT_BYTES) {
        unsigned short* Wt = (unsigned short*)d_ws;
        wt_pack<<<2048, 256, 0, stream>>>(Wix, Wih, Wbx, Wbh, Wt);
        lstm_fused<<<dim3(NCAT / BN, BATCH / BM), 256, 0, stream>>>(
            x, h, Wt, c, bix, bih, bbx, bbh, out_h, out_c);
    } else {
        naive_lstm<<<dim3(HID / 256, BATCH), 256, 0, stream>>>(
            x, h, c, Wix, bix, Wih, bih, Wbx, bbx, Wbh, bbh, out_h, out_c);
    }
}

// Round 6
// 234.350 us; speedup vs baseline: 1.2482x; 1.2482x over previous
//
#include <hip/hip_runtime.h>
#include <hip/hip_bf16.h>
#include <stdint.h>
#include <stddef.h>

// GlobalLSTMCell — f32 in/out, bf16 MFMA compute.
// R5 lesson: in-GEMM A-cvt loses (redundant ×32 along N, f32 fetch ×2) — packs
// restored. R6: core switched to mfma_f32_32x32x16_bf16 (8.07 cyc/32k FLOP vs
// 4.85/16k = -17% MFMA cycles), XOR chunk swizzle slot=r*4+(c^((r>>1)&3)) keeps
// gl2lds dest-contiguity AND b128 reads at bank floor; gates i,f|o,a pair per
// 32-wide n-tile, resolved with one shfl_xor(16) pair per reg in the epilogue.
// XCD 4x4 supertile swizzle for L2.

#define BATCH 4096
#define FEAT  1024
#define HID   1024
#define NCAT  4096
#define KCAT  2048

typedef __attribute__((ext_vector_type(8)))  __bf16 bf16x8;
typedef __attribute__((ext_vector_type(16))) float  floatx16;

__device__ __forceinline__ unsigned short f2bf(float f) {
    __hip_bfloat16 b = __float2bfloat16(f);
    return *reinterpret_cast<unsigned short*>(&b);
}
__device__ __forceinline__ void gl2lds16(const unsigned short* g, unsigned short* l) {
    __builtin_amdgcn_global_load_lds(
        (const __attribute__((address_space(1))) void*)g,
        (__attribute__((address_space(3))) void*)l, 16, 0, 0);
}

// ---------------- fused pack: Xcat + Wt ----------------
// blocks [0,2048): weight transpose tiles; blocks [2048,2560): xh rows (8 each).
// Wt[np][k]: np = (j>>4)*64 + g*16 + (j&15); g in {i,f,o,a}; k-contiguous bf16.
#define TP_PAD 72
__global__ __launch_bounds__(256)
void pack_all(const float* __restrict__ x, const float* __restrict__ h,
              const float* __restrict__ Wix, const float* __restrict__ Wih,
              const float* __restrict__ Wbx, const float* __restrict__ Wbh,
              unsigned short* __restrict__ Xcat, unsigned short* __restrict__ Wt) {
    __shared__ unsigned short tile[64 * TP_PAD];
    const int t = threadIdx.x;
    const int b = blockIdx.x;
    if (b >= 2048) {
        const int rb = (b - 2048) * 8;
#pragma unroll
        for (int it = 0; it < 8; ++it) {
            const int m = rb + it;
            const float* src = (t < 128) ? (x + (size_t)m * FEAT + t * 8)
                                         : (h + (size_t)m * HID + (t - 128) * 8);
            float4 v0 = *(const float4*)src;
            float4 v1 = *(const float4*)(src + 4);
            union { unsigned short s16[8]; uint4 v; } pk;
            pk.s16[0] = f2bf(v0.x); pk.s16[1] = f2bf(v0.y);
            pk.s16[2] = f2bf(v0.z); pk.s16[3] = f2bf(v0.w);
            pk.s16[4] = f2bf(v1.x); pk.s16[5] = f2bf(v1.y);
            pk.s16[6] = f2bf(v1.z); pk.s16[7] = f2bf(v1.w);
            *(uint4*)(Xcat + (size_t)m * KCAT + t * 8) = pk.v;
        }
        return;
    }
    const int k0 = (b & 31) * 64;
    const int q0 = (b >> 5) * 64;
    const float* src; int stride, cb;
    if (q0 < 3072) { src = (k0 < FEAT) ? Wix : Wih; stride = 3072; cb = q0; }
    else           { src = (k0 < FEAT) ? Wbx : Wbh; stride = 1024; cb = q0 - 3072; }
    const int krow = (k0 < FEAT) ? k0 : (k0 - FEAT);
    {
        int kl = t >> 2;
        int c0 = (t & 3) * 16;
        const float* s = src + (size_t)(krow + kl) * stride + cb + c0;
        union { unsigned short s16[16]; uint4 v[2]; } tmp;
#pragma unroll
        for (int u = 0; u < 16; u += 4) {
            float4 v = *(const float4*)(s + u);
            tmp.s16[u + 0] = f2bf(v.x); tmp.s16[u + 1] = f2bf(v.y);
            tmp.s16[u + 2] = f2bf(v.z); tmp.s16[u + 3] = f2bf(v.w);
        }
        *(uint4*)&tile[kl * TP_PAD + c0]     = tmp.v[0];
        *(uint4*)&tile[kl * TP_PAD + c0 + 8] = tmp.v[1];
    }
    __syncthreads();
    {
        int nl = t >> 2, seg = t & 3;
        int q = q0 + nl;
        int g, j;
        if (q < 3072) { g = q >> 10; j = q & 1023; }
        else          { g = 3;       j = q - 3072; }
        int np = ((j >> 4) << 6) + (g << 4) + (j & 15);
        union { unsigned short s16[16]; uint4 v[2]; } pk;
#pragma unroll
        for (int u = 0; u < 16; ++u)
            pk.s16[u] = tile[(seg * 16 + u) * TP_PAD + nl];
        uint4* dst = (uint4*)(Wt + (size_t)np * KCAT + k0 + seg * 16);
        dst[0] = pk.v[0];
        dst[1] = pk.v[1];
    }
}

// ---------------- fused GEMM (32x32x16 MFMA) + LSTM epilogue ----------------
#define BM 128
#define BN 128
#define BK 32

__global__ __launch_bounds__(256)
void lstm_fused(const unsigned short* __restrict__ Xcat,
                const unsigned short* __restrict__ Wt,
                const float* __restrict__ c_prev,
                const float* __restrict__ bix, const float* __restrict__ bih,
                const float* __restrict__ bbx, const float* __restrict__ bbh,
                float* __restrict__ out_h, float* __restrict__ out_c) {
    __shared__ unsigned short As[BM * BK];   // 8 KB
    __shared__ unsigned short Bs[BN * BK];   // 8 KB
    const int t    = threadIdx.x;
    const int lane = t & 63;
    const int wave = t >> 6;
    const int wm   = (wave >> 1) * 64;
    const int wn   = (wave & 1) * 64;

    // XCD-friendly 4x4 supertile swizzle of the 32x32 block grid.
    const int id = blockIdx.x;
    const int grp = id >> 4;
    const int bm = (grp & 7) * 4 + ((id >> 2) & 3);
    const int bn = (grp >> 3) * 4 + (id & 3);
    const int m0 = bm * BM;
    const int n0 = bn * BN;

    floatx16 acc[2][2];
#pragma unroll
    for (int i = 0; i < 2; ++i)
#pragma unroll
        for (int n = 0; n < 2; ++n)
#pragma unroll
            for (int q = 0; q < 16; ++q) acc[i][n][q] = 0.f;

    // Staging: physical slot s=t holds (row r=s>>2, chunk c=(s&3)^((r>>1)&3)).
    const int r  = t >> 2;
    const int cA = (((t & 3) ^ ((r >> 1) & 3)) * 8);

    // Fragment constants: chunk c of row rho at slot rho*4 + (c ^ ((rho>>1)&3)).
    const int rl  = lane & 31;
    const int hi  = lane >> 5;
    const int swz = (rl >> 1) & 3;

    for (int kk = 0; kk < KCAT; kk += BK) {
        __syncthreads();   // previous tile fully consumed
        gl2lds16(Xcat + (size_t)(m0 + r)      * KCAT + kk + cA, &As[t * 8]);
        gl2lds16(Xcat + (size_t)(m0 + r + 64) * KCAT + kk + cA, &As[t * 8 + 2048]);
        gl2lds16(Wt   + (size_t)(n0 + r)      * KCAT + kk + cA, &Bs[t * 8]);
        gl2lds16(Wt   + (size_t)(n0 + r + 64) * KCAT + kk + cA, &Bs[t * 8 + 2048]);
        __syncthreads();   // drains vmcnt(0)

#pragma unroll
        for (int ks = 0; ks < 2; ++ks) {
            const int co = (((ks * 2 + hi) ^ swz) * 8);
            bf16x8 a0 = *(const bf16x8*)&As[(wm +      rl) * BK + co];
            bf16x8 a1 = *(const bf16x8*)&As[(wm + 32 + rl) * BK + co];
            bf16x8 b0 = *(const bf16x8*)&Bs[(wn +      rl) * BK + co];
            bf16x8 b1 = *(const bf16x8*)&Bs[(wn + 32 + rl) * BK + co];
            acc[0][0] = __builtin_amdgcn_mfma_f32_32x32x16_bf16(a0, b0, acc[0][0], 0, 0, 0);
            acc[0][1] = __builtin_amdgcn_mfma_f32_32x32x16_bf16(a0, b1, acc[0][1], 0, 0, 0);
            acc[1][0] = __builtin_amdgcn_mfma_f32_32x32x16_bf16(a1, b0, acc[1][0], 0, 0, 0);
            acc[1][1] = __builtin_amdgcn_mfma_f32_32x32x16_bf16(a1, b1, acc[1][1], 0, 0, 0);
        }
    }

    // Epilogue. n' layout: n = J*64 + g*16 + jc. n-tile 0 (cols 0..31) = gates
    // i(lanes&16==0)|f; n-tile 1 = o|a. C/D: col=lane&31, row=(reg&3)+8*(reg>>2)+4*hi.
    // Lane pair (l, l^16) shares (rows, jc); l handles m-tile hl via shfl_xor(16).
    const int hl = (lane >> 4) & 1;
    const int jc = lane & 15;
    const int j  = (((n0 + wn) >> 6) << 4) + jc;
    const float bi = bix[j]           + bih[j];
    const float bf = bix[HID + j]     + bih[HID + j];
    const float bo = bix[2 * HID + j] + bih[2 * HID + j];
    const float ba = bbx[j]           + bbh[j];
    const int mbase = m0 + wm + hl * 32 + 4 * hi;
#pragma unroll
    for (int q = 0; q < 4; ++q) {
#pragma unroll
        for (int rr = 0; rr < 4; ++rr) {
            const int reg = q * 4 + rr;
            const int m   = mbase + q * 8 + rr;
            float own0  = hl ? acc[1][0][reg] : acc[0][0][reg];
            float own1  = hl ? acc[1][1][reg] : acc[0][1][reg];
            float send0 = hl ? acc[0][0][reg] : acc[1][0][reg];
            float send1 = hl ? acc[0][1][reg] : acc[1][1][reg];
            float recv0 = __shfl_xor(send0, 16, 64);
            float recv1 = __shfl_xor(send1, 16, 64);
            float gi = (hl ? recv0 : own0) + bi;
            float gf = (hl ? own0 : recv0) + bf;
            float go = (hl ? recv1 : own1) + bo;
            float ga = (hl ? own1 : recv1) + ba;
            float ig = 1.f / (1.f + __expf(-gi));
            float fg = 1.f / (1.f + __expf(-gf));
            float og = 1.f / (1.f + __expf(-go));
            float av = 2.f / (1.f + __expf(-2.f * ga)) - 1.f;
            float cp = c_prev[(size_t)m * HID + j];
            float cv = ig * av + fg * cp;
            float hv = og * (2.f / (1.f + __expf(-2.f * cv)) - 1.f);
            out_h[(size_t)m * HID + j] = hv;
            out_c[(size_t)m * HID + j] = cv;
        }
    }
}

// ---------------- naive fallback (ws too small) ----------------
__global__ void naive_lstm(const float* __restrict__ x, const float* __restrict__ h,
                           const float* __restrict__ cvp,
                           const float* __restrict__ Wix, const float* __restrict__ bix,
                           const float* __restrict__ Wih, const float* __restrict__ bih,
                           const float* __restrict__ Wbx, const float* __restrict__ bbx,
                           const float* __restrict__ Wbh, const float* __restrict__ bbh,
                           float* __restrict__ out_h, float* __restrict__ out_c) {
    const int j = blockIdx.x * 256 + threadIdx.x;
    const int m = blockIdx.y;
    float ai = 0.f, af = 0.f, ao = 0.f, aa = 0.f;
    for (int k = 0; k < FEAT; ++k) {
        float xk = x[(size_t)m * FEAT + k];
        ai += xk * Wix[(size_t)k * 3072 + j];
        af += xk * Wix[(size_t)k * 3072 + HID + j];
        ao += xk * Wix[(size_t)k * 3072 + 2 * HID + j];
        aa += xk * Wbx[(size_t)k * HID + j];
    }
    for (int k = 0; k < HID; ++k) {
        float hk = h[(size_t)m * HID + k];
        ai += hk * Wih[(size_t)k * 3072 + j];
        af += hk * Wih[(size_t)k * 3072 + HID + j];
        ao += hk * Wih[(size_t)k * 3072 + 2 * HID + j];
        aa += hk * Wbh[(size_t)k * HID + j];
    }
    ai += bix[j] + bih[j];
    af += bix[HID + j] + bih[HID + j];
    ao += bix[2 * HID + j] + bih[2 * HID + j];
    aa += bbx[j] + bbh[j];
    float ig = 1.f / (1.f + __expf(-ai));
    float fg = 1.f / (1.f + __expf(-af));
    float og = 1.f / (1.f + __expf(-ao));
    float av = 2.f / (1.f + __expf(-2.f * aa)) - 1.f;
    float cp = cvp[(size_t)m * HID + j];
    float cc = ig * av + fg * cp;
    float hh = og * (2.f / (1.f + __expf(-2.f * cc)) - 1.f);
    out_h[(size_t)m * HID + j] = hh;
    out_c[(size_t)m * HID + j] = cc;
}

extern "C" void kernel_launch(void* const* d_in, const int* in_sizes, int n_in,
                              void* d_out, int out_size, void* d_ws, size_t ws_size,
                              hipStream_t stream) {
    const float* x   = (const float*)d_in[0];
    const float* h   = (const float*)d_in[1];
    const float* c   = (const float*)d_in[2];
    const float* Wix = (const float*)d_in[3];
    const float* bix = (const float*)d_in[4];
    const float* Wih = (const float*)d_in[5];
    const float* bih = (const float*)d_in[6];
    const float* Wbx = (const float*)d_in[7];
    const float* bbx = (const float*)d_in[8];
    const float* Wbh = (const float*)d_in[9];
    const float* bbh = (const float*)d_in[10];

    float* out_h = (float*)d_out;
    float* out_c = out_h + (size_t)BATCH * HID;

    const size_t WT_BYTES = (size_t)NCAT * KCAT * 2;    // 16 MiB
    const size_t XC_BYTES = (size_t)BATCH * KCAT * 2;   // 16 MiB
    if (ws_size >= WT_BYTES + XC_BYTES) {
        unsigned short* Wt   = (unsigned short*)d_ws;
        unsigned short* Xcat = (unsigned short*)((char*)d_ws + WT_BYTES);
        pack_all<<<2048 + 512, 256, 0, stream>>>(x, h, Wix, Wih, Wbx, Wbh, Xcat, Wt);
        lstm_fused<<<1024, 256, 0, stream>>>(
            Xcat, Wt, c, bix, bih, bbx, bbh, out_h, out_c);
    } else {
        naive_lstm<<<dim3(HID / 256, BATCH), 256, 0, stream>>>(
            x, h, c, Wix, bix, Wih, bih, Wbx, bbx, Wbh, bbh, out_h, out_c);
    }
}